// Round 18
// baseline (324.397 us; speedup 1.0000x reference)
//
#include <hip/hip_runtime.h>
#include <math.h>

#define N_ROWS 262144
#define D_IN 64
#define RFF 256
#define NTILES (N_ROWS / 16)   // 16384
#define GRID 1024              // XCD-swizzled: nb = (b&7)*128 + (b>>3); h=nb&1, g=nb>>1

// d_out layout (floats): predictions[N*3] | AW[N*3] | reg_loss | alpha[256]
#define OFF_PRED 0
#define OFF_AW (N_ROWS * 3)
#define OFF_REG (2 * N_ROWS * 3)
#define OFF_ALPHA (2 * N_ROWS * 3 + 1)

// ws layout (floats): U[512] | BtP u32[768] @ [512,1280) ordered [half][128][3] |
//                     Wf f16x8 image @ [1280, 9472)
#define WS_B 512
#define WS_WF 1280

typedef _Float16 f16x8 __attribute__((ext_vector_type(8)));
typedef float f32x4 __attribute__((ext_vector_type(4)));
typedef float f32x2 __attribute__((ext_vector_type(2)));

__device__ __forceinline__ f32x4 mfma16(f16x8 a, f16x8 b, f32x4 c) {
    return __builtin_amdgcn_mfma_f32_16x16x32_f16(a, b, c, 0, 0, 0);
}

__device__ __forceinline__ unsigned short f32_to_bf16_rne(float x) {
    unsigned int u = __float_as_uint(x);
    unsigned int r = u + 0x7fffu + ((u >> 16) & 1u);
    return (unsigned short)(r >> 16);
}

// proj arrives in REVOLUTIONS (W pre-scaled by 1/2pi); hw trig after fract.
__device__ __forceinline__ void sincos_rev(float pr, float& sn, float& cs) {
    float f;
    asm("v_fract_f32 %0, %1" : "=v"(f) : "v"(pr));
    asm("v_sin_f32 %0, %1" : "=v"(sn) : "v"(f));
    asm("v_cos_f32 %0, %1" : "=v"(cs) : "v"(f));
}

// sum over the 16 lanes of a DPP row, pure VALU, result in all lanes
__device__ __forceinline__ float rowsum16(float x) {
    x += __int_as_float(__builtin_amdgcn_mov_dpp(__float_as_int(x), 0x121, 0xf, 0xf, true));
    x += __int_as_float(__builtin_amdgcn_mov_dpp(__float_as_int(x), 0x122, 0xf, 0xf, true));
    x += __int_as_float(__builtin_amdgcn_mov_dpp(__float_as_int(x), 0x124, 0xf, 0xf, true));
    x += __int_as_float(__builtin_amdgcn_mov_dpp(__float_as_int(x), 0x128, 0xf, 0xf, true));
    return x;
}

// async global->LDS, 16B per lane; LDS dest = base + lane*16 (wave-linear)
__device__ __forceinline__ void gload_lds16(const float* g, float* lds) {
    __builtin_amdgcn_global_load_lds(
        (const __attribute__((address_space(1))) unsigned int*)g,
        (__attribute__((address_space(3))) unsigned int*)(lds), 16, 0, 0);
}

#define WAITVM(N) do { asm volatile("s_waitcnt vmcnt(" #N ")" ::: "memory"); \
                       __builtin_amdgcn_sched_barrier(0); } while (0)
#define LGKM0()   do { asm volatile("s_waitcnt lgkmcnt(0)" ::: "memory"); \
                       __builtin_amdgcn_sched_barrier(0); } while (0)

// ---- k_prep: W fragment image (pre-scaled by 1/2pi) to ws; also zero U ----
__global__ __launch_bounds__(256) void k_prep(const float* __restrict__ W,
                                              float* __restrict__ ws) {
    const int e = blockIdx.x * 256 + threadIdx.x;  // 0..2047
    if (e < 512) ws[e] = 0.f;                      // U accumulators
    const int lane = e & 63;
    const int slot = e >> 6;
    const int kh = slot & 1;
    const int ct = slot >> 1;
    const int k0 = kh * 32 + 8 * (lane >> 4);
    const int col = ct * 16 + (lane & 15);
    f16x8 v;
#pragma unroll
    for (int i = 0; i < 8; ++i)
        v[i] = (_Float16)(W[(k0 + i) * RFF + col] * 0.15915494309189535f);
    *(f16x8*)(ws + WS_WF + e * 4) = v;
}

// 4 DMA ops for one 16x64 Z tile. LDS granule (row,g) = global (row, g^(row&7)).
__device__ __forceinline__ void stage_dma(const float* __restrict__ Z, int n0, int l,
                                          float* ldsbase) {
#pragma unroll
    for (int m = 0; m < 4; ++m) {
        const int row = m * 4 + (l >> 4);
        const int gc = (l & 15) ^ (row & 7);
        gload_lds16(Z + (size_t)(n0 + row) * D_IN + gc * 4, ldsbase + m * 256);
    }
}

// Read this lane's A-fragments (f16) from the swizzled tile (LGKM0 inside).
__device__ __forceinline__ void frags_from_lds(const float* bb, int lr, int lh,
                                               f16x8& ah0, f16x8& ah1) {
    const int s4 = lr & 7;
    const float* rp = bb + lr * 64;
    float z[16];
    *(float4*)&z[0]  = *(const float4*)(rp + (((lh * 2 + 0) ^ s4) << 2));
    *(float4*)&z[4]  = *(const float4*)(rp + (((lh * 2 + 1) ^ s4) << 2));
    *(float4*)&z[8]  = *(const float4*)(rp + (((lh * 2 + 8) ^ s4) << 2));
    *(float4*)&z[12] = *(const float4*)(rp + (((lh * 2 + 9) ^ s4) << 2));
    LGKM0();  // reads complete
#pragma unroll
    for (int i = 0; i < 8; ++i) {
        ah0[i] = (_Float16)z[i];
        ah1[i] = (_Float16)z[8 + i];
    }
}

// ---------------- Pass 1: U[f] partials (feature-half per block) ----------------
__global__ __launch_bounds__(256, 4) void k_pass1(const float* __restrict__ Z,
                                                  const float* __restrict__ ws_in,
                                                  float* __restrict__ U) {
    __shared__ float Zs[4][2048];  // 32 KB: per-wave SINGLE pair-buffer (2 tiles)
    __shared__ float Ured[256];    // 1 KB
    const int t = threadIdx.x;
    const int wv = t >> 6, l = t & 63, lr = l & 15, lh = l >> 4;
    const int nb = (blockIdx.x & 7) * 128 + (blockIdx.x >> 3);  // XCD swizzle
    const int h = nb & 1;
    const int g = nb >> 1;

    // W fragments straight into VGPRs (coalesced 16B/lane loads, no LDS)
    const float* wsWf = ws_in + WS_WF + h * 4096;
    f16x8 B[16];
#pragma unroll
    for (int s = 0; s < 16; ++s) B[s] = *(const f16x8*)(wsWf + s * 256 + l * 4);

    const int tstart = g * 32 + wv * 8;  // 8 tiles/wave = 4 rounds of 2
    stage_dma(Z, (tstart + 0) * 16, l, &Zs[wv][0]);
    stage_dma(Z, (tstart + 1) * 16, l, &Zs[wv][1024]);
    Ured[t] = 0.f;
    __syncthreads();  // drains vmcnt -> pair 0 + B ready; queue empty after

    f32x2 accC2[8], accS2[8];
#pragma unroll
    for (int c = 0; c < 8; ++c) { accC2[c] = (f32x2){0.f, 0.f}; accS2[c] = (f32x2){0.f, 0.f}; }

    for (int r = 0; r < 4; ++r) {
        // queue audit (FIFO, no stores): top of round r holds D(r)x8 (issued in
        // round r-1); WAITVM(0) retires them. r=0: queue empty -> no-op.
        WAITVM(0);
        f16x8 ah0, ah1, ah2, ah3;
        frags_from_lds(&Zs[wv][0], lr, lh, ah0, ah1);
        frags_from_lds(&Zs[wv][1024], lr, lh, ah2, ah3);  // LGKM0 -> buffer free
        if (r < 3) {
            stage_dma(Z, (tstart + 2 * r + 2) * 16, l, &Zs[wv][0]);
            stage_dma(Z, (tstart + 2 * r + 3) * 16, l, &Zs[wv][1024]);
            __builtin_amdgcn_sched_barrier(0);
        }
#pragma unroll
        for (int c = 0; c < 8; ++c) {
            f32x4 acc = (f32x4){0.f, 0.f, 0.f, 0.f};
            acc = mfma16(ah0, B[c * 2 + 0], acc);
            acc = mfma16(ah1, B[c * 2 + 1], acc);
            float sn0, cs0, sn1, cs1, sn2, cs2, sn3, cs3;
            sincos_rev(acc[0], sn0, cs0);
            sincos_rev(acc[1], sn1, cs1);
            sincos_rev(acc[2], sn2, cs2);
            sincos_rev(acc[3], sn3, cs3);
            accC2[c] += (f32x2){cs0, cs1};
            accC2[c] += (f32x2){cs2, cs3};
            accS2[c] += (f32x2){sn0, sn1};
            accS2[c] += (f32x2){sn2, sn3};
        }
#pragma unroll
        for (int c = 0; c < 8; ++c) {
            f32x4 acc = (f32x4){0.f, 0.f, 0.f, 0.f};
            acc = mfma16(ah2, B[c * 2 + 0], acc);
            acc = mfma16(ah3, B[c * 2 + 1], acc);
            float sn0, cs0, sn1, cs1, sn2, cs2, sn3, cs3;
            sincos_rev(acc[0], sn0, cs0);
            sincos_rev(acc[1], sn1, cs1);
            sincos_rev(acc[2], sn2, cs2);
            sincos_rev(acc[3], sn3, cs3);
            accC2[c] += (f32x2){cs0, cs1};
            accC2[c] += (f32x2){cs2, cs3};
            accS2[c] += (f32x2){sn0, sn1};
            accS2[c] += (f32x2){sn2, sn3};
        }
    }
#pragma unroll
    for (int c = 0; c < 8; ++c) {
        float cc = accC2[c][0] + accC2[c][1];
        float ss = accS2[c][0] + accS2[c][1];
        cc += __shfl_xor(cc, 16);
        cc += __shfl_xor(cc, 32);
        ss += __shfl_xor(ss, 16);
        ss += __shfl_xor(ss, 32);
        if (l < 16) {
            atomicAdd(&Ured[c * 16 + l], cc * 0.0625f);
            atomicAdd(&Ured[128 + c * 16 + l], ss * 0.0625f);
        }
    }
    __syncthreads();
    if (t < 128) atomicAdd(&U[128 * h + t], Ured[t]);
    else atomicAdd(&U[256 + 128 * h + (t - 128)], Ured[t]);
}

// ------------- Tiny kernel: alpha, packed B coefs (by half), reg_loss -------------
__global__ __launch_bounds__(256) void k_alpha(const float* __restrict__ U,
                                               const float* __restrict__ A,
                                               float* __restrict__ ws,
                                               float* __restrict__ out) {
    __shared__ float sm[256];
    __shared__ double gred[256];
    __shared__ double G6[6];
    const int k = threadIdx.x;

    const float am0 = (A[0] + A[1] + A[2]) * (1.0f / 3.0f);
    const float am1 = (A[3] + A[4] + A[5]) * (1.0f / 3.0f);
    float x = (am0 * U[2 * k] + am1 * U[2 * k + 1]) * (1.0f / (float)N_ROWS) * (1.0f / 1.6f);

    sm[k] = x;
    __syncthreads();
    for (int s = 128; s > 0; s >>= 1) {
        if (k < s) sm[k] = fmaxf(sm[k], sm[k + s]);
        __syncthreads();
    }
    float mx = sm[0];
    __syncthreads();
    float e = __expf(x - mx);
    sm[k] = e;
    __syncthreads();
    for (int s = 128; s > 0; s >>= 1) {
        if (k < s) sm[k] += sm[k + s];
        __syncthreads();
    }
    float al = e / sm[0];
    out[OFF_ALPHA + k] = al;
    sm[k] = al;
    __syncthreads();

    {   // packed coefs, ordered [half][128][3] for pass2's direct copy
        const float ac = 0.0625f * sm[k >> 1];
        const float as = 0.0625f * sm[128 + (k >> 1)];
        unsigned int* BtP = (unsigned int*)(ws + WS_B);
        const int dst = (k >> 7) * 384 + (k & 127) * 3;
#pragma unroll
        for (int j = 0; j < 3; ++j) {
            float bc = ac * A[k * 3 + j];
            float bs = as * A[(256 + k) * 3 + j];
            unsigned int ulo = f32_to_bf16_rne(bc);
            unsigned int uhi = f32_to_bf16_rne(bs);
            BtP[dst + j] = ulo | (uhi << 16);
        }
    }

    // nuclear norm of A (512x3): G = A^T A in double, closed-form eigs
    double af[2][3];
#pragma unroll
    for (int t2 = 0; t2 < 2; ++t2)
#pragma unroll
        for (int j = 0; j < 3; ++j) af[t2][j] = (double)A[(k + t2 * 256) * 3 + j];
    const int ei[6] = {0, 0, 0, 1, 1, 2};
    const int ej[6] = {0, 1, 2, 1, 2, 2};
    for (int eidx = 0; eidx < 6; ++eidx) {
        double p = af[0][ei[eidx]] * af[0][ej[eidx]] + af[1][ei[eidx]] * af[1][ej[eidx]];
        gred[k] = p;
        __syncthreads();
        for (int s = 128; s > 0; s >>= 1) {
            if (k < s) gred[k] += gred[k + s];
            __syncthreads();
        }
        if (k == 0) G6[eidx] = gred[0];
        __syncthreads();
    }
    if (k == 0) {
        double g00 = G6[0], g01 = G6[1], g02 = G6[2], g11 = G6[3], g12 = G6[4], g22 = G6[5];
        double q = (g00 + g11 + g22) / 3.0;
        double p1 = g01 * g01 + g02 * g02 + g12 * g12;
        double p2 = (g00 - q) * (g00 - q) + (g11 - q) * (g11 - q) + (g22 - q) * (g22 - q) + 2.0 * p1;
        double nuc;
        if (p2 < 1e-300) {
            nuc = 3.0 * sqrt(fmax(q, 0.0));
        } else {
            double p = sqrt(p2 / 6.0);
            double b00 = (g00 - q) / p, b11 = (g11 - q) / p, b22 = (g22 - q) / p;
            double b01 = g01 / p, b02 = g02 / p, b12 = g12 / p;
            double detB = b00 * (b11 * b22 - b12 * b12) - b01 * (b01 * b22 - b12 * b02) +
                          b02 * (b01 * b12 - b11 * b02);
            double rr = fmin(1.0, fmax(-1.0, detB / 2.0));
            double phi = acos(rr) / 3.0;
            double e1 = q + 2.0 * p * cos(phi);
            double e3 = q + 2.0 * p * cos(phi + 2.0943951023931953);
            double e2 = 3.0 * q - e1 - e3;
            nuc = sqrt(fmax(e1, 0.0)) + sqrt(fmax(e2, 0.0)) + sqrt(fmax(e3, 0.0));
        }
        out[OFF_REG] = (float)(0.01 * nuc);
    }
}

// ------- Pass 2: partial predictions; h=0 -> out[PRED], h=1 -> out[AW] (scratch) -------
__global__ __launch_bounds__(256, 4) void k_pass2(const float* __restrict__ Z,
                                                  const float* __restrict__ ws_in,
                                                  float* __restrict__ out) {
    __shared__ float Zs[4][2048];     // 32 KB pair-buffer
    __shared__ unsigned int BtP[384]; // 1.5 KB coefs for this half
    const int t = threadIdx.x;
    const int wv = t >> 6, l = t & 63, lr = l & 15, lh = l >> 4;
    const int nb = (blockIdx.x & 7) * 128 + (blockIdx.x >> 3);  // XCD swizzle
    const int h = nb & 1;
    const int g = nb >> 1;

    const float* wsWf = ws_in + WS_WF + h * 4096;
    f16x8 B[16];
#pragma unroll
    for (int s = 0; s < 16; ++s) B[s] = *(const f16x8*)(wsWf + s * 256 + l * 4);

    const int tstart = g * 32 + wv * 8;
    stage_dma(Z, (tstart + 0) * 16, l, &Zs[wv][0]);
    stage_dma(Z, (tstart + 1) * 16, l, &Zs[wv][1024]);
    {   // copy ALL 384 coef words with 256 threads (two strided steps)
        const unsigned int* src = (const unsigned int*)(ws_in + WS_B) + h * 384;
        BtP[t] = src[t];
        if (t < 128) BtP[256 + t] = src[256 + t];
    }
    __syncthreads();  // drains vmcnt (B + pair 0), BtP visible; queue empty

    const size_t ob = h ? (size_t)OFF_AW : (size_t)OFF_PRED;

    for (int r = 0; r < 4; ++r) {
        // queue audit (FIFO): top of round r holds D(r)x8, sA(r-1), sB(r-1)
        // ordered [D..8, sA, sB] -> WAITVM(2) retires D(r)x8, leaves 2 stores.
        // r=0: queue empty -> no-op.
        WAITVM(2);
        f16x8 ah0, ah1, ah2, ah3;
        frags_from_lds(&Zs[wv][0], lr, lh, ah0, ah1);
        frags_from_lds(&Zs[wv][1024], lr, lh, ah2, ah3);  // buffer free
        if (r < 3) {
            stage_dma(Z, (tstart + 2 * r + 2) * 16, l, &Zs[wv][0]);
            stage_dma(Z, (tstart + 2 * r + 3) * 16, l, &Zs[wv][1024]);
            __builtin_amdgcn_sched_barrier(0);
        }
        // ---- tile A (pa live range ends at its store) ----
        {
            const int n0 = (tstart + 2 * r) * 16;
            f32x2 pa01[3], pa23[3];
#pragma unroll
            for (int j = 0; j < 3; ++j) { pa01[j] = (f32x2){0.f, 0.f}; pa23[j] = (f32x2){0.f, 0.f}; }
#pragma unroll
            for (int c = 0; c < 8; ++c) {
                f32x4 acc = (f32x4){0.f, 0.f, 0.f, 0.f};
                acc = mfma16(ah0, B[c * 2 + 0], acc);
                acc = mfma16(ah1, B[c * 2 + 1], acc);
                const int fl = c * 16 + lr;
                unsigned int u0 = BtP[fl * 3 + 0], u1 = BtP[fl * 3 + 1], u2 = BtP[fl * 3 + 2];
                float sn0, cs0, sn1, cs1, sn2, cs2, sn3, cs3;
                sincos_rev(acc[0], sn0, cs0);
                sincos_rev(acc[1], sn1, cs1);
                sincos_rev(acc[2], sn2, cs2);
                sincos_rev(acc[3], sn3, cs3);
                const f32x2 cs01 = {cs0, cs1}, cs23 = {cs2, cs3};
                const f32x2 sn01 = {sn0, sn1}, sn23 = {sn2, sn3};
                const float bcf[3] = {__uint_as_float(u0 << 16), __uint_as_float(u1 << 16),
                                      __uint_as_float(u2 << 16)};
                const float bsf[3] = {__uint_as_float(u0 & 0xffff0000u),
                                      __uint_as_float(u1 & 0xffff0000u),
                                      __uint_as_float(u2 & 0xffff0000u)};
#pragma unroll
                for (int j = 0; j < 3; ++j) {
                    const f32x2 bc2 = {bcf[j], bcf[j]};
                    const f32x2 bs2 = {bsf[j], bsf[j]};
                    pa01[j] = __builtin_elementwise_fma(
                        cs01, bc2, __builtin_elementwise_fma(sn01, bs2, pa01[j]));
                    pa23[j] = __builtin_elementwise_fma(
                        cs23, bc2, __builtin_elementwise_fma(sn23, bs2, pa23[j]));
                }
            }
            float pa[4][3];
#pragma unroll
            for (int j = 0; j < 3; ++j) {
                pa[0][j] = rowsum16(pa01[j][0]);
                pa[1][j] = rowsum16(pa01[j][1]);
                pa[2][j] = rowsum16(pa23[j][0]);
                pa[3][j] = rowsum16(pa23[j][1]);
            }
            float val = 0.f;
#pragma unroll
            for (int rr = 0; rr < 4; ++rr)
#pragma unroll
                for (int j = 0; j < 3; ++j)
                    if (lr == rr * 3 + j) val = pa[rr][j];
            if (lr < 12) out[ob + ((size_t)n0 + 4 * lh) * 3 + lr] = val;
        }
        // ---- tile B ----
        {
            const int n0 = (tstart + 2 * r + 1) * 16;
            f32x2 pa01[3], pa23[3];
#pragma unroll
            for (int j = 0; j < 3; ++j) { pa01[j] = (f32x2){0.f, 0.f}; pa23[j] = (f32x2){0.f, 0.f}; }
#pragma unroll
            for (int c = 0; c < 8; ++c) {
                f32x4 acc = (f32x4){0.f, 0.f, 0.f, 0.f};
                acc = mfma16(ah2, B[c * 2 + 0], acc);
                acc = mfma16(ah3, B[c * 2 + 1], acc);
                const int fl = c * 16 + lr;
                unsigned int u0 = BtP[fl * 3 + 0], u1 = BtP[fl * 3 + 1], u2 = BtP[fl * 3 + 2];
                float sn0, cs0, sn1, cs1, sn2, cs2, sn3, cs3;
                sincos_rev(acc[0], sn0, cs0);
                sincos_rev(acc[1], sn1, cs1);
                sincos_rev(acc[2], sn2, cs2);
                sincos_rev(acc[3], sn3, cs3);
                const f32x2 cs01 = {cs0, cs1}, cs23 = {cs2, cs3};
                const f32x2 sn01 = {sn0, sn1}, sn23 = {sn2, sn3};
                const float bcf[3] = {__uint_as_float(u0 << 16), __uint_as_float(u1 << 16),
                                      __uint_as_float(u2 << 16)};
                const float bsf[3] = {__uint_as_float(u0 & 0xffff0000u),
                                      __uint_as_float(u1 & 0xffff0000u),
                                      __uint_as_float(u2 & 0xffff0000u)};
#pragma unroll
                for (int j = 0; j < 3; ++j) {
                    const f32x2 bc2 = {bcf[j], bcf[j]};
                    const f32x2 bs2 = {bsf[j], bsf[j]};
                    pa01[j] = __builtin_elementwise_fma(
                        cs01, bc2, __builtin_elementwise_fma(sn01, bs2, pa01[j]));
                    pa23[j] = __builtin_elementwise_fma(
                        cs23, bc2, __builtin_elementwise_fma(sn23, bs2, pa23[j]));
                }
            }
            float pa[4][3];
#pragma unroll
            for (int j = 0; j < 3; ++j) {
                pa[0][j] = rowsum16(pa01[j][0]);
                pa[1][j] = rowsum16(pa01[j][1]);
                pa[2][j] = rowsum16(pa23[j][0]);
                pa[3][j] = rowsum16(pa23[j][1]);
            }
            float val = 0.f;
#pragma unroll
            for (int rr = 0; rr < 4; ++rr)
#pragma unroll
                for (int j = 0; j < 3; ++j)
                    if (lr == rr * 3 + j) val = pa[rr][j];
            if (lr < 12) out[ob + ((size_t)n0 + 4 * lh) * 3 + lr] = val;
        }
    }
}

// ------- k_aw: pred = pA + pB; AW = row softmax(pred/16) -------
__global__ __launch_bounds__(256) void k_aw(float* __restrict__ out) {
    const size_t n = (size_t)blockIdx.x * 256 + threadIdx.x;
    const float a0 = out[OFF_PRED + n * 3 + 0], b0 = out[OFF_AW + n * 3 + 0];
    const float a1 = out[OFF_PRED + n * 3 + 1], b1 = out[OFF_AW + n * 3 + 1];
    const float a2 = out[OFF_PRED + n * 3 + 2], b2 = out[OFF_AW + n * 3 + 2];
    const float p0 = a0 + b0, p1 = a1 + b1, p2 = a2 + b2;
    out[OFF_PRED + n * 3 + 0] = p0;
    out[OFF_PRED + n * 3 + 1] = p1;
    out[OFF_PRED + n * 3 + 2] = p2;
    const float x0 = p0 * 0.0625f, x1 = p1 * 0.0625f, x2 = p2 * 0.0625f;
    const float m = fmaxf(x0, fmaxf(x1, x2));
    const float e0 = __expf(x0 - m), e1 = __expf(x1 - m), e2 = __expf(x2 - m);
    const float inv = 1.0f / (e0 + e1 + e2);
    out[OFF_AW + n * 3 + 0] = e0 * inv;
    out[OFF_AW + n * 3 + 1] = e1 * inv;
    out[OFF_AW + n * 3 + 2] = e2 * inv;
}

extern "C" void kernel_launch(void* const* d_in, const int* in_sizes, int n_in,
                              void* d_out, int out_size, void* d_ws, size_t ws_size,
                              hipStream_t stream) {
    const float* Z = (const float*)d_in[0];
    const float* W = (const float*)d_in[1];
    const float* A = (const float*)d_in[2];
    float* out = (float*)d_out;
    float* ws = (float*)d_ws;

    hipLaunchKernelGGL(k_prep, dim3(8), dim3(256), 0, stream, W, ws);
    hipLaunchKernelGGL(k_pass1, dim3(GRID), dim3(256), 0, stream, Z, ws, ws);
    hipLaunchKernelGGL(k_alpha, dim3(1), dim3(256), 0, stream, ws, A, ws, out);
    hipLaunchKernelGGL(k_pass2, dim3(GRID), dim3(256), 0, stream, Z, ws, out);
    hipLaunchKernelGGL(k_aw, dim3(N_ROWS / 256), dim3(256), 0, stream, out);
}

// Round 19
// 160.834 us; speedup vs baseline: 2.0170x; 2.0170x over previous
//
#include <hip/hip_runtime.h>
#include <math.h>

#define N_ROWS 262144
#define D_IN 64
#define RFF 256
#define NTILES (N_ROWS / 16)   // 16384
#define GRID 2048              // 8 blocks/CU; XCD swizzle: nb=(b&7)*256+(b>>3)

// d_out layout (floats): predictions[N*3] | AW[N*3] | reg_loss | alpha[256]
#define OFF_PRED 0
#define OFF_AW (N_ROWS * 3)
#define OFF_REG (2 * N_ROWS * 3)
#define OFF_ALPHA (2 * N_ROWS * 3 + 1)

// ws layout (floats): U[512] | BtP u32[768] @ [512,1280) ordered [half][128][3] |
//                     Wf f16x8 image @ [1280, 9472)
#define WS_B 512
#define WS_WF 1280

typedef _Float16 f16x8 __attribute__((ext_vector_type(8)));
typedef float f32x4 __attribute__((ext_vector_type(4)));
typedef float f32x2 __attribute__((ext_vector_type(2)));

__device__ __forceinline__ f32x4 mfma16(f16x8 a, f16x8 b, f32x4 c) {
    return __builtin_amdgcn_mfma_f32_16x16x32_f16(a, b, c, 0, 0, 0);
}

__device__ __forceinline__ unsigned short f32_to_bf16_rne(float x) {
    unsigned int u = __float_as_uint(x);
    unsigned int r = u + 0x7fffu + ((u >> 16) & 1u);
    return (unsigned short)(r >> 16);
}

// proj arrives in REVOLUTIONS (W pre-scaled by 1/2pi); hw trig after fract.
__device__ __forceinline__ void sincos_rev(float pr, float& sn, float& cs) {
    float f;
    asm("v_fract_f32 %0, %1" : "=v"(f) : "v"(pr));
    asm("v_sin_f32 %0, %1" : "=v"(sn) : "v"(f));
    asm("v_cos_f32 %0, %1" : "=v"(cs) : "v"(f));
}

// sum over the 16 lanes of a DPP row, pure VALU, result in all lanes
__device__ __forceinline__ float rowsum16(float x) {
    x += __int_as_float(__builtin_amdgcn_mov_dpp(__float_as_int(x), 0x121, 0xf, 0xf, true));
    x += __int_as_float(__builtin_amdgcn_mov_dpp(__float_as_int(x), 0x122, 0xf, 0xf, true));
    x += __int_as_float(__builtin_amdgcn_mov_dpp(__float_as_int(x), 0x124, 0xf, 0xf, true));
    x += __int_as_float(__builtin_amdgcn_mov_dpp(__float_as_int(x), 0x128, 0xf, 0xf, true));
    return x;
}

// async global->LDS, 16B per lane; LDS dest = base + lane*16 (wave-linear)
__device__ __forceinline__ void gload_lds16(const float* g, float* lds) {
    __builtin_amdgcn_global_load_lds(
        (const __attribute__((address_space(1))) unsigned int*)g,
        (__attribute__((address_space(3))) unsigned int*)(lds), 16, 0, 0);
}

#define WAITVM0() do { asm volatile("s_waitcnt vmcnt(0)" ::: "memory"); \
                       __builtin_amdgcn_sched_barrier(0); } while (0)
// pass2 loop: in-flight = 4 DMA (older) + 1 merged store (younger) -> wait to 1
#define WAITVM1() do { asm volatile("s_waitcnt vmcnt(1)" ::: "memory"); \
                       __builtin_amdgcn_sched_barrier(0); } while (0)
#define LGKM0()   do { asm volatile("s_waitcnt lgkmcnt(0)" ::: "memory"); \
                       __builtin_amdgcn_sched_barrier(0); } while (0)

// ---- k_prep: W fragment image (pre-scaled by 1/2pi) to ws; also zero U ----
__global__ __launch_bounds__(256) void k_prep(const float* __restrict__ W,
                                              float* __restrict__ ws) {
    const int e = blockIdx.x * 256 + threadIdx.x;  // 0..2047
    if (e < 512) ws[e] = 0.f;                      // U accumulators
    const int lane = e & 63;
    const int slot = e >> 6;
    const int kh = slot & 1;
    const int ct = slot >> 1;
    const int k0 = kh * 32 + 8 * (lane >> 4);
    const int col = ct * 16 + (lane & 15);
    f16x8 v;
#pragma unroll
    for (int i = 0; i < 8; ++i)
        v[i] = (_Float16)(W[(k0 + i) * RFF + col] * 0.15915494309189535f);
    *(f16x8*)(ws + WS_WF + e * 4) = v;
}

// 4 DMA ops for one 16x64 Z tile. LDS granule (row,g) = global (row, g^(row&7)).
__device__ __forceinline__ void stage_dma(const float* __restrict__ Z, int n0, int l,
                                          float* ldsbase) {
#pragma unroll
    for (int m = 0; m < 4; ++m) {
        const int row = m * 4 + (l >> 4);
        const int gc = (l & 15) ^ (row & 7);
        gload_lds16(Z + (size_t)(n0 + row) * D_IN + gc * 4, ldsbase + m * 256);
    }
}

// Read this lane's A-fragments (f16) from the swizzled tile.
__device__ __forceinline__ void frags_from_lds(const float* bb, int lr, int lh,
                                               f16x8& ah0, f16x8& ah1) {
    const int s4 = lr & 7;
    const float* rp = bb + lr * 64;
    float z[16];
    *(float4*)&z[0]  = *(const float4*)(rp + (((lh * 2 + 0) ^ s4) << 2));
    *(float4*)&z[4]  = *(const float4*)(rp + (((lh * 2 + 1) ^ s4) << 2));
    *(float4*)&z[8]  = *(const float4*)(rp + (((lh * 2 + 8) ^ s4) << 2));
    *(float4*)&z[12] = *(const float4*)(rp + (((lh * 2 + 9) ^ s4) << 2));
    LGKM0();  // reads complete -> buffer free for next DMA
#pragma unroll
    for (int i = 0; i < 8; ++i) {
        ah0[i] = (_Float16)z[i];
        ah1[i] = (_Float16)z[8 + i];
    }
}

// ---------------- Pass 1: U[f] partials (feature-half per block) ----------------
__global__ __launch_bounds__(256, 4) void k_pass1(const float* __restrict__ Z,
                                                  const float* __restrict__ ws_in,
                                                  float* __restrict__ U) {
    __shared__ float Zs[4][1024];  // 16 KB: per-wave single buffer
    __shared__ float Ured[256];    // 1 KB
    const int t = threadIdx.x;
    const int wv = t >> 6, l = t & 63, lr = l & 15, lh = l >> 4;
    const int nb = (blockIdx.x & 7) * 256 + (blockIdx.x >> 3);  // XCD swizzle
    const int h = nb & 1;
    const int g = nb >> 1;  // 0..1023, 16 tiles per group

    // W fragments straight into VGPRs (coalesced 16B/lane loads, no LDS)
    const float* wsWf = ws_in + WS_WF + h * 4096;
    f16x8 B[16];
#pragma unroll
    for (int s = 0; s < 16; ++s) B[s] = *(const f16x8*)(wsWf + s * 256 + l * 4);

    const int tstart = g * 16 + wv * 4;  // 4 tiles per wave
    stage_dma(Z, tstart * 16, l, &Zs[wv][0]);
    Ured[t] = 0.f;
    __syncthreads();  // drains vmcnt -> first tile + B ready

    f32x2 accC2[8], accS2[8];
#pragma unroll
    for (int c = 0; c < 8; ++c) { accC2[c] = (f32x2){0.f, 0.f}; accS2[c] = (f32x2){0.f, 0.f}; }

    for (int tt = 0; tt < 4; ++tt) {
        if (tt) WAITVM0();
        f16x8 ah0, ah1;
        frags_from_lds(&Zs[wv][0], lr, lh, ah0, ah1);  // LGKM0 frees buf
        if (tt < 3) {
            stage_dma(Z, (tstart + tt + 1) * 16, l, &Zs[wv][0]);
            __builtin_amdgcn_sched_barrier(0);
        }
#pragma unroll
        for (int c = 0; c < 8; ++c) {
            f32x4 acc = (f32x4){0.f, 0.f, 0.f, 0.f};
            acc = mfma16(ah0, B[c * 2 + 0], acc);
            acc = mfma16(ah1, B[c * 2 + 1], acc);
            float sn0, cs0, sn1, cs1, sn2, cs2, sn3, cs3;
            sincos_rev(acc[0], sn0, cs0);
            sincos_rev(acc[1], sn1, cs1);
            sincos_rev(acc[2], sn2, cs2);
            sincos_rev(acc[3], sn3, cs3);
            accC2[c] += (f32x2){cs0, cs1};
            accC2[c] += (f32x2){cs2, cs3};
            accS2[c] += (f32x2){sn0, sn1};
            accS2[c] += (f32x2){sn2, sn3};
        }
    }
#pragma unroll
    for (int c = 0; c < 8; ++c) {
        float cc = accC2[c][0] + accC2[c][1];
        float ss = accS2[c][0] + accS2[c][1];
        cc += __shfl_xor(cc, 16);
        cc += __shfl_xor(cc, 32);
        ss += __shfl_xor(ss, 16);
        ss += __shfl_xor(ss, 32);
        if (l < 16) {
            atomicAdd(&Ured[c * 16 + l], cc * 0.0625f);
            atomicAdd(&Ured[128 + c * 16 + l], ss * 0.0625f);
        }
    }
    __syncthreads();
    if (t < 128) atomicAdd(&U[128 * h + t], Ured[t]);
    else atomicAdd(&U[256 + 128 * h + (t - 128)], Ured[t]);
}

// ------------- Tiny kernel: alpha, packed B coefs (by half), reg_loss -------------
__global__ __launch_bounds__(256) void k_alpha(const float* __restrict__ U,
                                               const float* __restrict__ A,
                                               float* __restrict__ ws,
                                               float* __restrict__ out) {
    __shared__ float sm[256];
    __shared__ double gred[256];
    __shared__ double G6[6];
    const int k = threadIdx.x;

    const float am0 = (A[0] + A[1] + A[2]) * (1.0f / 3.0f);
    const float am1 = (A[3] + A[4] + A[5]) * (1.0f / 3.0f);
    float x = (am0 * U[2 * k] + am1 * U[2 * k + 1]) * (1.0f / (float)N_ROWS) * (1.0f / 1.6f);

    sm[k] = x;
    __syncthreads();
    for (int s = 128; s > 0; s >>= 1) {
        if (k < s) sm[k] = fmaxf(sm[k], sm[k + s]);
        __syncthreads();
    }
    float mx = sm[0];
    __syncthreads();
    float e = __expf(x - mx);
    sm[k] = e;
    __syncthreads();
    for (int s = 128; s > 0; s >>= 1) {
        if (k < s) sm[k] += sm[k + s];
        __syncthreads();
    }
    float al = e / sm[0];
    out[OFF_ALPHA + k] = al;
    sm[k] = al;
    __syncthreads();

    {   // packed coefs, ordered [half][128][3] for pass2's direct copy
        const float ac = 0.0625f * sm[k >> 1];
        const float as = 0.0625f * sm[128 + (k >> 1)];
        unsigned int* BtP = (unsigned int*)(ws + WS_B);
        const int dst = (k >> 7) * 384 + (k & 127) * 3;
#pragma unroll
        for (int j = 0; j < 3; ++j) {
            float bc = ac * A[k * 3 + j];
            float bs = as * A[(256 + k) * 3 + j];
            unsigned int ulo = f32_to_bf16_rne(bc);
            unsigned int uhi = f32_to_bf16_rne(bs);
            BtP[dst + j] = ulo | (uhi << 16);
        }
    }

    // nuclear norm of A (512x3): G = A^T A in double, closed-form eigs
    double af[2][3];
#pragma unroll
    for (int t2 = 0; t2 < 2; ++t2)
#pragma unroll
        for (int j = 0; j < 3; ++j) af[t2][j] = (double)A[(k + t2 * 256) * 3 + j];
    const int ei[6] = {0, 0, 0, 1, 1, 2};
    const int ej[6] = {0, 1, 2, 1, 2, 2};
    for (int eidx = 0; eidx < 6; ++eidx) {
        double p = af[0][ei[eidx]] * af[0][ej[eidx]] + af[1][ei[eidx]] * af[1][ej[eidx]];
        gred[k] = p;
        __syncthreads();
        for (int s = 128; s > 0; s >>= 1) {
            if (k < s) gred[k] += gred[k + s];
            __syncthreads();
        }
        if (k == 0) G6[eidx] = gred[0];
        __syncthreads();
    }
    if (k == 0) {
        double g00 = G6[0], g01 = G6[1], g02 = G6[2], g11 = G6[3], g12 = G6[4], g22 = G6[5];
        double q = (g00 + g11 + g22) / 3.0;
        double p1 = g01 * g01 + g02 * g02 + g12 * g12;
        double p2 = (g00 - q) * (g00 - q) + (g11 - q) * (g11 - q) + (g22 - q) * (g22 - q) + 2.0 * p1;
        double nuc;
        if (p2 < 1e-300) {
            nuc = 3.0 * sqrt(fmax(q, 0.0));
        } else {
            double p = sqrt(p2 / 6.0);
            double b00 = (g00 - q) / p, b11 = (g11 - q) / p, b22 = (g22 - q) / p;
            double b01 = g01 / p, b02 = g02 / p, b12 = g12 / p;
            double detB = b00 * (b11 * b22 - b12 * b12) - b01 * (b01 * b22 - b12 * b02) +
                          b02 * (b01 * b12 - b11 * b02);
            double rr = fmin(1.0, fmax(-1.0, detB / 2.0));
            double phi = acos(rr) / 3.0;
            double e1 = q + 2.0 * p * cos(phi);
            double e3 = q + 2.0 * p * cos(phi + 2.0943951023931953);
            double e2 = 3.0 * q - e1 - e3;
            nuc = sqrt(fmax(e1, 0.0)) + sqrt(fmax(e2, 0.0)) + sqrt(fmax(e3, 0.0));
        }
        out[OFF_REG] = (float)(0.01 * nuc);
    }
}

// ------- Pass 2: partial predictions; h=0 -> out[PRED], h=1 -> out[AW] (scratch) -------
__global__ __launch_bounds__(256, 4) void k_pass2(const float* __restrict__ Z,
                                                  const float* __restrict__ ws_in,
                                                  float* __restrict__ out) {
    __shared__ float Zs[4][1024];     // 16 KB
    __shared__ unsigned int BtP[384]; // 1.5 KB coefs for this half
    const int t = threadIdx.x;
    const int wv = t >> 6, l = t & 63, lr = l & 15, lh = l >> 4;
    const int nb = (blockIdx.x & 7) * 256 + (blockIdx.x >> 3);  // XCD swizzle
    const int h = nb & 1;
    const int g = nb >> 1;

    const float* wsWf = ws_in + WS_WF + h * 4096;
    f16x8 B[16];
#pragma unroll
    for (int s = 0; s < 16; ++s) B[s] = *(const f16x8*)(wsWf + s * 256 + l * 4);

    const int tstart = g * 16 + wv * 4;
    stage_dma(Z, tstart * 16, l, &Zs[wv][0]);
    {   // copy ALL 384 coef words with 256 threads (two strided steps)
        const unsigned int* src = (const unsigned int*)(ws_in + WS_B) + h * 384;
        BtP[t] = src[t];
        if (t < 128) BtP[256 + t] = src[256 + t];
    }
    __syncthreads();  // drains vmcnt (B + tile0), BtP visible

    const size_t ob = h ? (size_t)OFF_AW : (size_t)OFF_PRED;

    for (int tt = 0; tt < 4; ++tt) {
        const int n0 = (tstart + tt) * 16;
        if (tt) WAITVM1();  // 4 older DMAs drained; 1 merged store may linger
        f16x8 ah0, ah1;
        frags_from_lds(&Zs[wv][0], lr, lh, ah0, ah1);  // LGKM0 frees buf
        if (tt < 3) {
            stage_dma(Z, (tstart + tt + 1) * 16, l, &Zs[wv][0]);
            __builtin_amdgcn_sched_barrier(0);
        }
        f32x2 pa01[3], pa23[3];
#pragma unroll
        for (int j = 0; j < 3; ++j) { pa01[j] = (f32x2){0.f, 0.f}; pa23[j] = (f32x2){0.f, 0.f}; }
#pragma unroll
        for (int c = 0; c < 8; ++c) {
            f32x4 acc = (f32x4){0.f, 0.f, 0.f, 0.f};
            acc = mfma16(ah0, B[c * 2 + 0], acc);
            acc = mfma16(ah1, B[c * 2 + 1], acc);
            const int fl = c * 16 + lr;
            unsigned int u0 = BtP[fl * 3 + 0], u1 = BtP[fl * 3 + 1], u2 = BtP[fl * 3 + 2];
            float sn0, cs0, sn1, cs1, sn2, cs2, sn3, cs3;
            sincos_rev(acc[0], sn0, cs0);
            sincos_rev(acc[1], sn1, cs1);
            sincos_rev(acc[2], sn2, cs2);
            sincos_rev(acc[3], sn3, cs3);
            const f32x2 cs01 = {cs0, cs1}, cs23 = {cs2, cs3};
            const f32x2 sn01 = {sn0, sn1}, sn23 = {sn2, sn3};
            const float bcf[3] = {__uint_as_float(u0 << 16), __uint_as_float(u1 << 16),
                                  __uint_as_float(u2 << 16)};
            const float bsf[3] = {__uint_as_float(u0 & 0xffff0000u),
                                  __uint_as_float(u1 & 0xffff0000u),
                                  __uint_as_float(u2 & 0xffff0000u)};
#pragma unroll
            for (int j = 0; j < 3; ++j) {
                const f32x2 bc2 = {bcf[j], bcf[j]};
                const f32x2 bs2 = {bsf[j], bsf[j]};
                pa01[j] = __builtin_elementwise_fma(
                    cs01, bc2, __builtin_elementwise_fma(sn01, bs2, pa01[j]));
                pa23[j] = __builtin_elementwise_fma(
                    cs23, bc2, __builtin_elementwise_fma(sn23, bs2, pa23[j]));
            }
        }
        float pa[4][3];
#pragma unroll
        for (int j = 0; j < 3; ++j) {
            pa[0][j] = rowsum16(pa01[j][0]);
            pa[1][j] = rowsum16(pa01[j][1]);
            pa[2][j] = rowsum16(pa23[j][0]);
            pa[3][j] = rowsum16(pa23[j][1]);
        }
        // ONE store instruction per wave: lane lr<12 writes dword (row=lr/3, j=lr%3)
        float val = 0.f;
#pragma unroll
        for (int r = 0; r < 4; ++r)
#pragma unroll
            for (int j = 0; j < 3; ++j)
                if (lr == r * 3 + j) val = pa[r][j];
        if (lr < 12) {
            out[ob + ((size_t)n0 + 4 * lh) * 3 + lr] = val;
        }
    }
}

// ------- k_aw: pred = pA + pB; AW = row softmax(pred/16) -------
__global__ __launch_bounds__(256) void k_aw(float* __restrict__ out) {
    const size_t n = (size_t)blockIdx.x * 256 + threadIdx.x;
    const float a0 = out[OFF_PRED + n * 3 + 0], b0 = out[OFF_AW + n * 3 + 0];
    const float a1 = out[OFF_PRED + n * 3 + 1], b1 = out[OFF_AW + n * 3 + 1];
    const float a2 = out[OFF_PRED + n * 3 + 2], b2 = out[OFF_AW + n * 3 + 2];
    const float p0 = a0 + b0, p1 = a1 + b1, p2 = a2 + b2;
    out[OFF_PRED + n * 3 + 0] = p0;
    out[OFF_PRED + n * 3 + 1] = p1;
    out[OFF_PRED + n * 3 + 2] = p2;
    const float x0 = p0 * 0.0625f, x1 = p1 * 0.0625f, x2 = p2 * 0.0625f;
    const float m = fmaxf(x0, fmaxf(x1, x2));
    const float e0 = __expf(x0 - m), e1 = __expf(x1 - m), e2 = __expf(x2 - m);
    const float inv = 1.0f / (e0 + e1 + e2);
    out[OFF_AW + n * 3 + 0] = e0 * inv;
    out[OFF_AW + n * 3 + 1] = e1 * inv;
    out[OFF_AW + n * 3 + 2] = e2 * inv;
}

extern "C" void kernel_launch(void* const* d_in, const int* in_sizes, int n_in,
                              void* d_out, int out_size, void* d_ws, size_t ws_size,
                              hipStream_t stream) {
    const float* Z = (const float*)d_in[0];
    const float* W = (const float*)d_in[1];
    const float* A = (const float*)d_in[2];
    float* out = (float*)d_out;
    float* ws = (float*)d_ws;

    hipLaunchKernelGGL(k_prep, dim3(8), dim3(256), 0, stream, W, ws);
    hipLaunchKernelGGL(k_pass1, dim3(GRID), dim3(256), 0, stream, Z, ws, ws);
    hipLaunchKernelGGL(k_alpha, dim3(1), dim3(256), 0, stream, ws, A, ws, out);
    hipLaunchKernelGGL(k_pass2, dim3(GRID), dim3(256), 0, stream, Z, ws, out);
    hipLaunchKernelGGL(k_aw, dim3(N_ROWS / 256), dim3(256), 0, stream, out);
}

// Round 20
// 80.692 us; speedup vs baseline: 4.0202x; 1.9932x over previous
//
#include <hip/hip_runtime.h>
#include <math.h>

#define N_ROWS 262144
#define D_IN 64
#define RFF 256
#define NTILES (N_ROWS / 16)   // 16384
#define GRID 1024              // XCD-swizzled: nb = (b&7)*128 + (b>>3); h=nb&1, g=nb>>1

// d_out layout (floats): predictions[N*3] | AW[N*3] | reg_loss | alpha[256]
#define OFF_PRED 0
#define OFF_AW (N_ROWS * 3)
#define OFF_REG (2 * N_ROWS * 3)
#define OFF_ALPHA (2 * N_ROWS * 3 + 1)

// ws layout (floats): U[512] | BtP u32[768] @ [512,1280) ordered [half][128][3] |
//                     Wf f16x8 image @ [1280, 9472)
#define WS_B 512
#define WS_WF 1280

typedef _Float16 f16x8 __attribute__((ext_vector_type(8)));
typedef float f32x4 __attribute__((ext_vector_type(4)));
typedef float f32x2 __attribute__((ext_vector_type(2)));

__device__ __forceinline__ f32x4 mfma16(f16x8 a, f16x8 b, f32x4 c) {
    return __builtin_amdgcn_mfma_f32_16x16x32_f16(a, b, c, 0, 0, 0);
}

__device__ __forceinline__ unsigned short f32_to_bf16_rne(float x) {
    unsigned int u = __float_as_uint(x);
    unsigned int r = u + 0x7fffu + ((u >> 16) & 1u);
    return (unsigned short)(r >> 16);
}

// proj arrives in REVOLUTIONS (W pre-scaled by 1/2pi); hw trig after fract.
__device__ __forceinline__ void sincos_rev(float pr, float& sn, float& cs) {
    float f;
    asm("v_fract_f32 %0, %1" : "=v"(f) : "v"(pr));
    asm("v_sin_f32 %0, %1" : "=v"(sn) : "v"(f));
    asm("v_cos_f32 %0, %1" : "=v"(cs) : "v"(f));
}

// sum over the 16 lanes of a DPP row, pure VALU, result in all lanes
__device__ __forceinline__ float rowsum16(float x) {
    x += __int_as_float(__builtin_amdgcn_mov_dpp(__float_as_int(x), 0x121, 0xf, 0xf, true));
    x += __int_as_float(__builtin_amdgcn_mov_dpp(__float_as_int(x), 0x122, 0xf, 0xf, true));
    x += __int_as_float(__builtin_amdgcn_mov_dpp(__float_as_int(x), 0x124, 0xf, 0xf, true));
    x += __int_as_float(__builtin_amdgcn_mov_dpp(__float_as_int(x), 0x128, 0xf, 0xf, true));
    return x;
}

// async global->LDS, 16B per lane; LDS dest = base + lane*16 (wave-linear)
__device__ __forceinline__ void gload_lds16(const float* g, float* lds) {
    __builtin_amdgcn_global_load_lds(
        (const __attribute__((address_space(1))) unsigned int*)g,
        (__attribute__((address_space(3))) unsigned int*)(lds), 16, 0, 0);
}

#define WAITVM0() do { asm volatile("s_waitcnt vmcnt(0)" ::: "memory"); \
                       __builtin_amdgcn_sched_barrier(0); } while (0)
// pass2 loop: in-flight = 4 DMA (older) + 1 merged store (younger) -> wait to 1
#define WAITVM1() do { asm volatile("s_waitcnt vmcnt(1)" ::: "memory"); \
                       __builtin_amdgcn_sched_barrier(0); } while (0)
#define LGKM0()   do { asm volatile("s_waitcnt lgkmcnt(0)" ::: "memory"); \
                       __builtin_amdgcn_sched_barrier(0); } while (0)

// ---- k_prep: W fragment image (pre-scaled by 1/2pi) to ws; also zero U ----
__global__ __launch_bounds__(256) void k_prep(const float* __restrict__ W,
                                              float* __restrict__ ws) {
    const int e = blockIdx.x * 256 + threadIdx.x;  // 0..2047
    if (e < 512) ws[e] = 0.f;                      // U accumulators
    const int lane = e & 63;
    const int slot = e >> 6;
    const int kh = slot & 1;
    const int ct = slot >> 1;
    const int k0 = kh * 32 + 8 * (lane >> 4);
    const int col = ct * 16 + (lane & 15);
    f16x8 v;
#pragma unroll
    for (int i = 0; i < 8; ++i)
        v[i] = (_Float16)(W[(k0 + i) * RFF + col] * 0.15915494309189535f);
    *(f16x8*)(ws + WS_WF + e * 4) = v;
}

// 4 DMA ops for one 16x64 Z tile. LDS granule (row,g) = global (row, g^(row&7)).
__device__ __forceinline__ void stage_dma(const float* __restrict__ Z, int n0, int l,
                                          float* ldsbase) {
#pragma unroll
    for (int m = 0; m < 4; ++m) {
        const int row = m * 4 + (l >> 4);
        const int gc = (l & 15) ^ (row & 7);
        gload_lds16(Z + (size_t)(n0 + row) * D_IN + gc * 4, ldsbase + m * 256);
    }
}

// Read this lane's A-fragments (f16) from the swizzled tile.
__device__ __forceinline__ void frags_from_lds(const float* bb, int lr, int lh,
                                               f16x8& ah0, f16x8& ah1) {
    const int s4 = lr & 7;
    const float* rp = bb + lr * 64;
    float z[16];
    *(float4*)&z[0]  = *(const float4*)(rp + (((lh * 2 + 0) ^ s4) << 2));
    *(float4*)&z[4]  = *(const float4*)(rp + (((lh * 2 + 1) ^ s4) << 2));
    *(float4*)&z[8]  = *(const float4*)(rp + (((lh * 2 + 8) ^ s4) << 2));
    *(float4*)&z[12] = *(const float4*)(rp + (((lh * 2 + 9) ^ s4) << 2));
    LGKM0();  // reads complete -> buffer free for next DMA
#pragma unroll
    for (int i = 0; i < 8; ++i) {
        ah0[i] = (_Float16)z[i];
        ah1[i] = (_Float16)z[8 + i];
    }
}

// ---------------- Pass 1: U[f] partials (feature-half per block) ----------------
__global__ __launch_bounds__(256, 4) void k_pass1(const float* __restrict__ Z,
                                                  const float* __restrict__ ws_in,
                                                  float* __restrict__ U) {
    __shared__ float Zs[4][1024];  // 16 KB: per-wave single buffer
    __shared__ float Ured[256];    // 1 KB
    const int t = threadIdx.x;
    const int wv = t >> 6, l = t & 63, lr = l & 15, lh = l >> 4;
    const int nb = (blockIdx.x & 7) * 128 + (blockIdx.x >> 3);  // XCD swizzle
    const int h = nb & 1;
    const int g = nb >> 1;

    // W fragments straight into VGPRs (coalesced 16B/lane loads, no LDS)
    const float* wsWf = ws_in + WS_WF + h * 4096;
    f16x8 B[16];
#pragma unroll
    for (int s = 0; s < 16; ++s) B[s] = *(const f16x8*)(wsWf + s * 256 + l * 4);

    const int tstart = g * 32 + wv * 8;
    stage_dma(Z, tstart * 16, l, &Zs[wv][0]);
    Ured[t] = 0.f;
    __syncthreads();  // drains vmcnt -> first tile + B ready

    // scalar accumulators: 16 VGPRs (vs 32 packed) - keeps body under budget
    float accC[8], accS[8];
#pragma unroll
    for (int c = 0; c < 8; ++c) { accC[c] = 0.f; accS[c] = 0.f; }

    for (int tt = 0; tt < 8; ++tt) {
        if (tt) WAITVM0();
        f16x8 ah0, ah1;
        frags_from_lds(&Zs[wv][0], lr, lh, ah0, ah1);  // LGKM0 frees buf
        if (tt < 7) {
            stage_dma(Z, (tstart + tt + 1) * 16, l, &Zs[wv][0]);
            __builtin_amdgcn_sched_barrier(0);
        }
#pragma unroll
        for (int c = 0; c < 8; ++c) {
            f32x4 acc = (f32x4){0.f, 0.f, 0.f, 0.f};
            acc = mfma16(ah0, B[c * 2 + 0], acc);
            acc = mfma16(ah1, B[c * 2 + 1], acc);
            float sn0, cs0, sn1, cs1, sn2, cs2, sn3, cs3;
            sincos_rev(acc[0], sn0, cs0);
            sincos_rev(acc[1], sn1, cs1);
            sincos_rev(acc[2], sn2, cs2);
            sincos_rev(acc[3], sn3, cs3);
            accC[c] += (cs0 + cs1) + (cs2 + cs3);
            accS[c] += (sn0 + sn1) + (sn2 + sn3);
        }
    }
#pragma unroll
    for (int c = 0; c < 8; ++c) {
        float cc = accC[c];
        float ss = accS[c];
        cc += __shfl_xor(cc, 16);
        cc += __shfl_xor(cc, 32);
        ss += __shfl_xor(ss, 16);
        ss += __shfl_xor(ss, 32);
        if (l < 16) {
            atomicAdd(&Ured[c * 16 + l], cc * 0.0625f);
            atomicAdd(&Ured[128 + c * 16 + l], ss * 0.0625f);
        }
    }
    __syncthreads();
    if (t < 128) atomicAdd(&U[128 * h + t], Ured[t]);
    else atomicAdd(&U[256 + 128 * h + (t - 128)], Ured[t]);
}

// ------------- Tiny kernel: alpha, packed B coefs (by half), reg_loss -------------
__global__ __launch_bounds__(256) void k_alpha(const float* __restrict__ U,
                                               const float* __restrict__ A,
                                               float* __restrict__ ws,
                                               float* __restrict__ out) {
    __shared__ float sm[256];
    __shared__ double gred[256];
    __shared__ double G6[6];
    const int k = threadIdx.x;

    const float am0 = (A[0] + A[1] + A[2]) * (1.0f / 3.0f);
    const float am1 = (A[3] + A[4] + A[5]) * (1.0f / 3.0f);
    float x = (am0 * U[2 * k] + am1 * U[2 * k + 1]) * (1.0f / (float)N_ROWS) * (1.0f / 1.6f);

    sm[k] = x;
    __syncthreads();
    for (int s = 128; s > 0; s >>= 1) {
        if (k < s) sm[k] = fmaxf(sm[k], sm[k + s]);
        __syncthreads();
    }
    float mx = sm[0];
    __syncthreads();
    float e = __expf(x - mx);
    sm[k] = e;
    __syncthreads();
    for (int s = 128; s > 0; s >>= 1) {
        if (k < s) sm[k] += sm[k + s];
        __syncthreads();
    }
    float al = e / sm[0];
    out[OFF_ALPHA + k] = al;
    sm[k] = al;
    __syncthreads();

    {   // packed coefs, ordered [half][128][3] for pass2's direct copy
        const float ac = 0.0625f * sm[k >> 1];
        const float as = 0.0625f * sm[128 + (k >> 1)];
        unsigned int* BtP = (unsigned int*)(ws + WS_B);
        const int dst = (k >> 7) * 384 + (k & 127) * 3;
#pragma unroll
        for (int j = 0; j < 3; ++j) {
            float bc = ac * A[k * 3 + j];
            float bs = as * A[(256 + k) * 3 + j];
            unsigned int ulo = f32_to_bf16_rne(bc);
            unsigned int uhi = f32_to_bf16_rne(bs);
            BtP[dst + j] = ulo | (uhi << 16);
        }
    }

    // nuclear norm of A (512x3): G = A^T A in double, closed-form eigs
    double af[2][3];
#pragma unroll
    for (int t2 = 0; t2 < 2; ++t2)
#pragma unroll
        for (int j = 0; j < 3; ++j) af[t2][j] = (double)A[(k + t2 * 256) * 3 + j];
    const int ei[6] = {0, 0, 0, 1, 1, 2};
    const int ej[6] = {0, 1, 2, 1, 2, 2};
    for (int eidx = 0; eidx < 6; ++eidx) {
        double p = af[0][ei[eidx]] * af[0][ej[eidx]] + af[1][ei[eidx]] * af[1][ej[eidx]];
        gred[k] = p;
        __syncthreads();
        for (int s = 128; s > 0; s >>= 1) {
            if (k < s) gred[k] += gred[k + s];
            __syncthreads();
        }
        if (k == 0) G6[eidx] = gred[0];
        __syncthreads();
    }
    if (k == 0) {
        double g00 = G6[0], g01 = G6[1], g02 = G6[2], g11 = G6[3], g12 = G6[4], g22 = G6[5];
        double q = (g00 + g11 + g22) / 3.0;
        double p1 = g01 * g01 + g02 * g02 + g12 * g12;
        double p2 = (g00 - q) * (g00 - q) + (g11 - q) * (g11 - q) + (g22 - q) * (g22 - q) + 2.0 * p1;
        double nuc;
        if (p2 < 1e-300) {
            nuc = 3.0 * sqrt(fmax(q, 0.0));
        } else {
            double p = sqrt(p2 / 6.0);
            double b00 = (g00 - q) / p, b11 = (g11 - q) / p, b22 = (g22 - q) / p;
            double b01 = g01 / p, b02 = g02 / p, b12 = g12 / p;
            double detB = b00 * (b11 * b22 - b12 * b12) - b01 * (b01 * b22 - b12 * b02) +
                          b02 * (b01 * b12 - b11 * b02);
            double rr = fmin(1.0, fmax(-1.0, detB / 2.0));
            double phi = acos(rr) / 3.0;
            double e1 = q + 2.0 * p * cos(phi);
            double e3 = q + 2.0 * p * cos(phi + 2.0943951023931953);
            double e2 = 3.0 * q - e1 - e3;
            nuc = sqrt(fmax(e1, 0.0)) + sqrt(fmax(e2, 0.0)) + sqrt(fmax(e3, 0.0));
        }
        out[OFF_REG] = (float)(0.01 * nuc);
    }
}

// ------- Pass 2: partial predictions; h=0 -> out[PRED], h=1 -> out[AW] (scratch) -------
__global__ __launch_bounds__(256, 4) void k_pass2(const float* __restrict__ Z,
                                                  const float* __restrict__ ws_in,
                                                  float* __restrict__ out) {
    __shared__ float Zs[4][1024];     // 16 KB
    __shared__ unsigned int BtP[384]; // 1.5 KB coefs for this half
    const int t = threadIdx.x;
    const int wv = t >> 6, l = t & 63, lr = l & 15, lh = l >> 4;
    const int nb = (blockIdx.x & 7) * 128 + (blockIdx.x >> 3);  // XCD swizzle
    const int h = nb & 1;
    const int g = nb >> 1;

    const float* wsWf = ws_in + WS_WF + h * 4096;
    f16x8 B[16];
#pragma unroll
    for (int s = 0; s < 16; ++s) B[s] = *(const f16x8*)(wsWf + s * 256 + l * 4);

    const int tstart = g * 32 + wv * 8;
    stage_dma(Z, tstart * 16, l, &Zs[wv][0]);
    {   // copy ALL 384 coef words with 256 threads (two strided steps)
        const unsigned int* src = (const unsigned int*)(ws_in + WS_B) + h * 384;
        BtP[t] = src[t];
        if (t < 128) BtP[256 + t] = src[256 + t];
    }
    __syncthreads();  // drains vmcnt (B + tile0), BtP visible

    const size_t ob = h ? (size_t)OFF_AW : (size_t)OFF_PRED;

    for (int tt = 0; tt < 8; ++tt) {
        const int n0 = (tstart + tt) * 16;
        if (tt) WAITVM1();  // 4 older DMAs drained; 1 merged store may linger
        f16x8 ah0, ah1;
        frags_from_lds(&Zs[wv][0], lr, lh, ah0, ah1);  // LGKM0 frees buf
        if (tt < 7) {
            stage_dma(Z, (tstart + tt + 1) * 16, l, &Zs[wv][0]);
            __builtin_amdgcn_sched_barrier(0);
        }
        f32x2 pa01[3], pa23[3];
#pragma unroll
        for (int j = 0; j < 3; ++j) { pa01[j] = (f32x2){0.f, 0.f}; pa23[j] = (f32x2){0.f, 0.f}; }
#pragma unroll
        for (int c = 0; c < 8; ++c) {
            f32x4 acc = (f32x4){0.f, 0.f, 0.f, 0.f};
            acc = mfma16(ah0, B[c * 2 + 0], acc);
            acc = mfma16(ah1, B[c * 2 + 1], acc);
            const int fl = c * 16 + lr;
            unsigned int u0 = BtP[fl * 3 + 0], u1 = BtP[fl * 3 + 1], u2 = BtP[fl * 3 + 2];
            float sn0, cs0, sn1, cs1, sn2, cs2, sn3, cs3;
            sincos_rev(acc[0], sn0, cs0);
            sincos_rev(acc[1], sn1, cs1);
            sincos_rev(acc[2], sn2, cs2);
            sincos_rev(acc[3], sn3, cs3);
            const f32x2 cs01 = {cs0, cs1}, cs23 = {cs2, cs3};
            const f32x2 sn01 = {sn0, sn1}, sn23 = {sn2, sn3};
            const float bcf[3] = {__uint_as_float(u0 << 16), __uint_as_float(u1 << 16),
                                  __uint_as_float(u2 << 16)};
            const float bsf[3] = {__uint_as_float(u0 & 0xffff0000u),
                                  __uint_as_float(u1 & 0xffff0000u),
                                  __uint_as_float(u2 & 0xffff0000u)};
#pragma unroll
            for (int j = 0; j < 3; ++j) {
                const f32x2 bc2 = {bcf[j], bcf[j]};
                const f32x2 bs2 = {bsf[j], bsf[j]};
                pa01[j] = __builtin_elementwise_fma(
                    cs01, bc2, __builtin_elementwise_fma(sn01, bs2, pa01[j]));
                pa23[j] = __builtin_elementwise_fma(
                    cs23, bc2, __builtin_elementwise_fma(sn23, bs2, pa23[j]));
            }
        }
        float pa[4][3];
#pragma unroll
        for (int j = 0; j < 3; ++j) {
            pa[0][j] = rowsum16(pa01[j][0]);
            pa[1][j] = rowsum16(pa01[j][1]);
            pa[2][j] = rowsum16(pa23[j][0]);
            pa[3][j] = rowsum16(pa23[j][1]);
        }
        // ONE store instruction per wave: lane lr<12 writes dword (row=lr/3, j=lr%3)
        float val = 0.f;
#pragma unroll
        for (int r = 0; r < 4; ++r)
#pragma unroll
            for (int j = 0; j < 3; ++j)
                if (lr == r * 3 + j) val = pa[r][j];
        if (lr < 12) {
            out[ob + ((size_t)n0 + 4 * lh) * 3 + lr] = val;
        }
    }
}

// ------- k_aw: pred = pA + pB; AW = row softmax(pred/16) -------
__global__ __launch_bounds__(256) void k_aw(float* __restrict__ out) {
    const size_t n = (size_t)blockIdx.x * 256 + threadIdx.x;
    const float a0 = out[OFF_PRED + n * 3 + 0], b0 = out[OFF_AW + n * 3 + 0];
    const float a1 = out[OFF_PRED + n * 3 + 1], b1 = out[OFF_AW + n * 3 + 1];
    const float a2 = out[OFF_PRED + n * 3 + 2], b2 = out[OFF_AW + n * 3 + 2];
    const float p0 = a0 + b0, p1 = a1 + b1, p2 = a2 + b2;
    out[OFF_PRED + n * 3 + 0] = p0;
    out[OFF_PRED + n * 3 + 1] = p1;
    out[OFF_PRED + n * 3 + 2] = p2;
    const float x0 = p0 * 0.0625f, x1 = p1 * 0.0625f, x2 = p2 * 0.0625f;
    const float m = fmaxf(x0, fmaxf(x1, x2));
    const float e0 = __expf(x0 - m), e1 = __expf(x1 - m), e2 = __expf(x2 - m);
    const float inv = 1.0f / (e0 + e1 + e2);
    out[OFF_AW + n * 3 + 0] = e0 * inv;
    out[OFF_AW + n * 3 + 1] = e1 * inv;
    out[OFF_AW + n * 3 + 2] = e2 * inv;
}

extern "C" void kernel_launch(void* const* d_in, const int* in_sizes, int n_in,
                              void* d_out, int out_size, void* d_ws, size_t ws_size,
                              hipStream_t stream) {
    const float* Z = (const float*)d_in[0];
    const float* W = (const float*)d_in[1];
    const float* A = (const float*)d_in[2];
    float* out = (float*)d_out;
    float* ws = (float*)d_ws;

    hipLaunchKernelGGL(k_prep, dim3(8), dim3(256), 0, stream, W, ws);
    hipLaunchKernelGGL(k_pass1, dim3(GRID), dim3(256), 0, stream, Z, ws, ws);
    hipLaunchKernelGGL(k_alpha, dim3(1), dim3(256), 0, stream, ws, A, ws, out);
    hipLaunchKernelGGL(k_pass2, dim3(GRID), dim3(256), 0, stream, Z, ws, out);
    hipLaunchKernelGGL(k_aw, dim3(N_ROWS / 256), dim3(256), 0, stream, out);
}